// Round 4
// baseline (290.364 us; speedup 1.0000x reference)
//
#include <hip/hip_runtime.h>
#include <math.h>

#define DELTA      0.04f
#define LOG_CLAMP  -100.0f
#define N          2048
#define ROWS_PER_BLOCK 4
#define BLOCK      256

// One WAVE per row; no LDS, no barriers. ALL row data is loaded up-front into
// register arrays (24 global_load_dwordx4 issued back-to-back) so one memory
// latency covers the whole row -- R3 showed the compiler otherwise serializes
// loads (VGPR=36, VALUBusy 9.8%, latency-bound at ~79us).
//   A[16]: anchors row as float4 (2 points each)  -> squared-dist argmin,
//          first-index tie-break (per-lane k-ascending + butterfly index cmp)
//   C[8]:  conf row as float4 -> overwritten in place with exp(conf)
// Butterfly (shfl_xor) reductions converge every lane to identical values
// (bitwise deterministic). CE via per-lane product of (1-p) + ONE __logf.
__global__ __launch_bounds__(BLOCK) void row_kernel(
    const float* __restrict__ anchors,   // B x N x 2
    const float* __restrict__ offsets,   // B x N x 2
    const float* __restrict__ conf,      // B x N
    const float* __restrict__ gt,        // B x 2
    float2* __restrict__ part)           // B x (ce, hu)
{
    const int wid  = threadIdx.x >> 6;
    const int lane = threadIdx.x & 63;
    const int b    = blockIdx.x * ROWS_PER_BLOCK + wid;

    const float4* __restrict__ arow4 = (const float4*)(anchors + (size_t)b * N * 2); // 1024
    const float4* __restrict__ crow4 = (const float4*)(conf + (size_t)b * N);        // 512
    const float2 g = ((const float2*)gt)[b];

    // ---- hoisted loads: 16 anchor float4 + 8 conf float4 per lane ----
    float4 A[16];
    float4 C[8];
    #pragma unroll
    for (int k = 0; k < 16; ++k) A[k] = arow4[k * 64 + lane];
    #pragma unroll
    for (int k = 0; k < 8; ++k)  C[k] = crow4[k * 64 + lane];

    // ---- argmin of squared distance (consumes A in issue order) ----
    float dmin = INFINITY;
    int   imin = 0;
    #pragma unroll
    for (int k = 0; k < 16; ++k) {
        const int f = k * 64 + lane;          // float4 index = point pair 2f,2f+1
        float dx, dy, d;
        dx = A[k].x - g.x; dy = A[k].y - g.y; d = dx * dx + dy * dy;
        if (d < dmin) { dmin = d; imin = 2 * f; }
        dx = A[k].z - g.x; dy = A[k].w - g.y; d = dx * dx + dy * dy;
        if (d < dmin) { dmin = d; imin = 2 * f + 1; }
    }

    // ---- exp in place + sum ----
    float sume = 0.0f;
    #pragma unroll
    for (int k = 0; k < 8; ++k) {
        C[k].x = __expf(C[k].x);
        C[k].y = __expf(C[k].y);
        C[k].z = __expf(C[k].z);
        C[k].w = __expf(C[k].w);
        sume += (C[k].x + C[k].y) + (C[k].z + C[k].w);
    }

    // ---- butterfly reduce: all lanes converge to identical values ----
    #pragma unroll
    for (int off = 1; off < 64; off <<= 1) {
        const float d2 = __shfl_xor(dmin, off, 64);
        const int   i2 = __shfl_xor(imin, off, 64);
        if (d2 < dmin || (d2 == dmin && i2 < imin)) { dmin = d2; imin = i2; }
        sume += __shfl_xor(sume, off, 64);
    }
    const float inv = 1.0f / sume;

    // ---- sum log(1-p) via per-lane product + one hardware log ----
    float prod = 1.0f;
    #pragma unroll
    for (int k = 0; k < 8; ++k) {
        prod *= fmaf(-C[k].x, inv, 1.0f) * fmaf(-C[k].y, inv, 1.0f)
              * fmaf(-C[k].z, inv, 1.0f) * fmaf(-C[k].w, inv, 1.0f);
    }
    float slog = __logf(fmaxf(prod, 1e-37f));   // underflow guard; unreachable here
    #pragma unroll
    for (int off = 1; off < 64; off <<= 1)
        slog += __shfl_xor(slog, off, 64);

    if (lane == 0) {
        const int ci = imin;
        // three independent gathers, issued concurrently (row is L2-hot)
        const float  cci = (conf + (size_t)b * N)[ci];
        const float2 ca  = ((const float2*)(anchors + (size_t)b * N * 2))[ci];
        const float2 co  = ((const float2*)(offsets + (size_t)b * N * 2))[ci];

        const float p_ci = __expf(cci) * inv;
        const float logp = fmaxf(__logf(p_ci),        LOG_CLAMP);
        const float l1mp = fmaxf(__logf(1.0f - p_ci), LOG_CLAMP);
        const float ce = -(logp + (slog - l1mp));

        const float x0 = co.x - (g.x - ca.x);
        const float x1 = co.y - (g.y - ca.y);
        const float a0 = fabsf(x0);
        const float a1 = fabsf(x1);
        const float h0 = (a0 <= DELTA) ? 0.5f * x0 * x0 : DELTA * (a0 - 0.5f * DELTA);
        const float h1 = (a1 <= DELTA) ? 0.5f * x1 * x1 : DELTA * (a1 - 0.5f * DELTA);

        part[b] = make_float2(ce, h0 + h1);
    }
}

// Single-block deterministic final reduce (double accumulate), 1024 threads.
__global__ __launch_bounds__(1024) void reduce_kernel(
    const float2* __restrict__ part,
    float* __restrict__ out, int nrows)
{
    double ce = 0.0, hu = 0.0;
    for (int i = threadIdx.x; i < nrows; i += 1024) {
        const float2 p = part[i];
        ce += (double)p.x;
        hu += (double)p.y;
    }
    #pragma unroll
    for (int off = 32; off > 0; off >>= 1) {
        ce += __shfl_down(ce, off, 64);
        hu += __shfl_down(hu, off, 64);
    }
    __shared__ double sc[16], sh[16];
    const int wid = threadIdx.x >> 6, lane = threadIdx.x & 63;
    if (lane == 0) { sc[wid] = ce; sh[wid] = hu; }
    __syncthreads();
    if (threadIdx.x == 0) {
        double tce = 0.0, thu = 0.0;
        #pragma unroll
        for (int w = 0; w < 16; ++w) { tce += sc[w]; thu += sh[w]; }
        out[0] = (float)(tce + thu);
        out[1] = (float)tce;
        out[2] = (float)thu;
    }
}

extern "C" void kernel_launch(void* const* d_in, const int* in_sizes, int n_in,
                              void* d_out, int out_size, void* d_ws, size_t ws_size,
                              hipStream_t stream) {
    const float* anchors = (const float*)d_in[0];
    const float* offsets = (const float*)d_in[1];
    const float* conf    = (const float*)d_in[2];
    const float* gt      = (const float*)d_in[3];
    float* out = (float*)d_out;

    const int B = in_sizes[3] / 2;   // ground_truth is (B, 2)

    float2* part = (float2*)d_ws;    // B float2 partials

    row_kernel<<<B / ROWS_PER_BLOCK, BLOCK, 0, stream>>>(anchors, offsets, conf, gt, part);
    reduce_kernel<<<1, 1024, 0, stream>>>(part, out, B);
}

// Round 5
// 287.187 us; speedup vs baseline: 1.0111x; 1.0111x over previous
//
#include <hip/hip_runtime.h>
#include <math.h>

#define DELTA      0.04f
#define LOG_CLAMP  -100.0f
#define N          2048
#define ROWS_PER_BLOCK 4
#define BLOCK      256

// One WAVE per row; no LDS, no barriers. ALL row data (16 anchor float4 +
// 8 conf float4 per lane) is issued as 24 back-to-back global_load_dwordx4
// BEFORE any consumption. R3/R4 post-mortem: the machine scheduler sank the
// hoisted loads back into the consume loops (VGPR stayed 36 -> 1 outstanding
// load/wave -> congestion-inflated ~4200cy effective latency -> 2.55 TB/s
// delivered cap). __builtin_amdgcn_sched_barrier(0) pins the loads above the
// consumers; the register file must then hold all 96 floats (VGPR >= ~110 is
// the success tell).
__global__ __launch_bounds__(BLOCK) void row_kernel(
    const float* __restrict__ anchors,   // B x N x 2
    const float* __restrict__ offsets,   // B x N x 2
    const float* __restrict__ conf,      // B x N
    const float* __restrict__ gt,        // B x 2
    float2* __restrict__ part)           // B x (ce, hu)
{
    const int wid  = threadIdx.x >> 6;
    const int lane = threadIdx.x & 63;
    const int b    = blockIdx.x * ROWS_PER_BLOCK + wid;

    const float4* __restrict__ arow4 = (const float4*)(anchors + (size_t)b * N * 2); // 1024
    const float4* __restrict__ crow4 = (const float4*)(conf + (size_t)b * N);        // 512
    const float2 g = ((const float2*)gt)[b];

    // ---- issue ALL loads up front: 16 anchor float4 + 8 conf float4 ----
    float4 A[16];
    float4 C[8];
    #pragma unroll
    for (int k = 0; k < 16; ++k) A[k] = arow4[k * 64 + lane];
    #pragma unroll
    for (int k = 0; k < 8; ++k)  C[k] = crow4[k * 64 + lane];

    // nothing may cross this point: loads stay issued back-to-back above
    __builtin_amdgcn_sched_barrier(0);

    // ---- argmin of squared distance (A loads return first) ----
    float dmin = INFINITY;
    int   imin = 0;
    #pragma unroll
    for (int k = 0; k < 16; ++k) {
        const int f = k * 64 + lane;          // float4 index = point pair 2f,2f+1
        float dx, dy, d;
        dx = A[k].x - g.x; dy = A[k].y - g.y; d = dx * dx + dy * dy;
        if (d < dmin) { dmin = d; imin = 2 * f; }
        dx = A[k].z - g.x; dy = A[k].w - g.y; d = dx * dx + dy * dy;
        if (d < dmin) { dmin = d; imin = 2 * f + 1; }
    }

    // ---- exp in place + sum ----
    float sume = 0.0f;
    #pragma unroll
    for (int k = 0; k < 8; ++k) {
        C[k].x = __expf(C[k].x);
        C[k].y = __expf(C[k].y);
        C[k].z = __expf(C[k].z);
        C[k].w = __expf(C[k].w);
        sume += (C[k].x + C[k].y) + (C[k].z + C[k].w);
    }

    // ---- butterfly reduce: all lanes converge to identical values ----
    #pragma unroll
    for (int off = 1; off < 64; off <<= 1) {
        const float d2 = __shfl_xor(dmin, off, 64);
        const int   i2 = __shfl_xor(imin, off, 64);
        if (d2 < dmin || (d2 == dmin && i2 < imin)) { dmin = d2; imin = i2; }
        sume += __shfl_xor(sume, off, 64);
    }
    const float inv = 1.0f / sume;

    // ---- sum log(1-p) via per-lane product + one hardware log ----
    float prod = 1.0f;
    #pragma unroll
    for (int k = 0; k < 8; ++k) {
        prod *= fmaf(-C[k].x, inv, 1.0f) * fmaf(-C[k].y, inv, 1.0f)
              * fmaf(-C[k].z, inv, 1.0f) * fmaf(-C[k].w, inv, 1.0f);
    }
    float slog = __logf(fmaxf(prod, 1e-37f));   // underflow guard; unreachable here
    #pragma unroll
    for (int off = 1; off < 64; off <<= 1)
        slog += __shfl_xor(slog, off, 64);

    if (lane == 0) {
        const int ci = imin;
        // three independent gathers, issued concurrently (row is L2-hot)
        const float  cci = (conf + (size_t)b * N)[ci];
        const float2 ca  = ((const float2*)(anchors + (size_t)b * N * 2))[ci];
        const float2 co  = ((const float2*)(offsets + (size_t)b * N * 2))[ci];

        const float p_ci = __expf(cci) * inv;
        const float logp = fmaxf(__logf(p_ci),        LOG_CLAMP);
        const float l1mp = fmaxf(__logf(1.0f - p_ci), LOG_CLAMP);
        const float ce = -(logp + (slog - l1mp));

        const float x0 = co.x - (g.x - ca.x);
        const float x1 = co.y - (g.y - ca.y);
        const float a0 = fabsf(x0);
        const float a1 = fabsf(x1);
        const float h0 = (a0 <= DELTA) ? 0.5f * x0 * x0 : DELTA * (a0 - 0.5f * DELTA);
        const float h1 = (a1 <= DELTA) ? 0.5f * x1 * x1 : DELTA * (a1 - 0.5f * DELTA);

        part[b] = make_float2(ce, h0 + h1);
    }
}

// Single-block deterministic final reduce (double accumulate), 1024 threads.
__global__ __launch_bounds__(1024) void reduce_kernel(
    const float2* __restrict__ part,
    float* __restrict__ out, int nrows)
{
    double ce = 0.0, hu = 0.0;
    for (int i = threadIdx.x; i < nrows; i += 1024) {
        const float2 p = part[i];
        ce += (double)p.x;
        hu += (double)p.y;
    }
    #pragma unroll
    for (int off = 32; off > 0; off >>= 1) {
        ce += __shfl_down(ce, off, 64);
        hu += __shfl_down(hu, off, 64);
    }
    __shared__ double sc[16], sh[16];
    const int wid = threadIdx.x >> 6, lane = threadIdx.x & 63;
    if (lane == 0) { sc[wid] = ce; sh[wid] = hu; }
    __syncthreads();
    if (threadIdx.x == 0) {
        double tce = 0.0, thu = 0.0;
        #pragma unroll
        for (int w = 0; w < 16; ++w) { tce += sc[w]; thu += sh[w]; }
        out[0] = (float)(tce + thu);
        out[1] = (float)tce;
        out[2] = (float)thu;
    }
}

extern "C" void kernel_launch(void* const* d_in, const int* in_sizes, int n_in,
                              void* d_out, int out_size, void* d_ws, size_t ws_size,
                              hipStream_t stream) {
    const float* anchors = (const float*)d_in[0];
    const float* offsets = (const float*)d_in[1];
    const float* conf    = (const float*)d_in[2];
    const float* gt      = (const float*)d_in[3];
    float* out = (float*)d_out;

    const int B = in_sizes[3] / 2;   // ground_truth is (B, 2)

    float2* part = (float2*)d_ws;    // B float2 partials

    row_kernel<<<B / ROWS_PER_BLOCK, BLOCK, 0, stream>>>(anchors, offsets, conf, gt, part);
    reduce_kernel<<<1, 1024, 0, stream>>>(part, out, B);
}